// Round 2
// baseline (392.993 us; speedup 1.0000x reference)
//
#include <hip/hip_runtime.h>

#define T_LEN 2048
#define HID 16

typedef __attribute__((ext_vector_type(8))) short short8v;
typedef __attribute__((ext_vector_type(4))) float float4v;
typedef __attribute__((ext_vector_type(4))) unsigned int uint4v;

// truncation-packed bf16 pair: word = [bf16(a) | bf16(b)<<16]
__device__ __forceinline__ unsigned pack_bf16_trunc(float a, float b) {
  unsigned ua = __builtin_bit_cast(unsigned, a);
  unsigned ub = __builtin_bit_cast(unsigned, b);
  return (ua >> 16) | (ub & 0xFFFF0000u);
}
// residual h - bf16_trunc(h); exactly representable in fp32
__device__ __forceinline__ float bf16_resid(float h) {
  unsigned u = __builtin_bit_cast(unsigned, h) & 0xFFFF0000u;
  return h - __builtin_bit_cast(float, u);
}

// tanh(y) = 1 - 2/(exp2(2*log2e*y)+1), input clamped so result is always finite
__device__ __forceinline__ float fast_tanh(float y) {
  float t = y * 2.885390081777927f;
  t = fminf(fmaxf(t, -126.0f), 126.0f);
  float e = __builtin_amdgcn_exp2f(t);
  float r = __builtin_amdgcn_rcpf(e + 1.0f);
  return fmaf(-2.0f, r, 1.0f);
}

// One wave = 16 batch columns, mfma_f32_16x16x32_bf16 (m89-verified layouts):
//   A: lane l holds A[l&15][8*(l>>4)+v]   (8 bf16)
//   B: lane l holds B[8*(l>>4)+v][l&15]   (8 bf16)
//   D: lane l holds D[4*(l>>4)+r][l&15]   (4 f32)
// K-row content (my choice): g0: h_hi[0..7], g1: h_lo[0..7], g2: h_hi[8..15], g3: h_lo[8..15]
//   A1 = W_hi[:, 8*(g>>1)..+7]  -> A1*B = W_hi*h_hi + W_hi*h_lo
//   A2 = even g ? W_lo[:, 8*(g>>1)..+7] : 0 -> A2*B = W_lo*h_hi
// Repack D->B needs one shfl_xor(16): own 4 rows + partner 4 rows cover the 8 needed.
__global__ __launch_bounds__(256) void elman_kernel(
    const float* __restrict__ x, const float* __restrict__ Wih,
    const float* __restrict__ Whh, const float* __restrict__ bih,
    const float* __restrict__ bhh, const float* __restrict__ fcw,
    const float* __restrict__ fcb, float* __restrict__ out) {
  const int tid  = threadIdx.x;
  const int lane = tid & 63;
  const int wv   = tid >> 6;
  const int grp  = blockIdx.x * 4 + wv;
  const int g    = lane >> 4;          // k-block / D-row group
  const int j    = lane & 15;          // batch col n; also A row m
  const int b    = grp * 16 + j;
  const bool odd = (g & 1) != 0;
  const int colbase = (g >> 1) * 8;

  // ---- A operands from W_hh ----
  const float* wrow = Whh + j * HID + colbase;
  float4v wa = *reinterpret_cast<const float4v*>(wrow);
  float4v wb = *reinterpret_cast<const float4v*>(wrow + 4);
  float w0 = wa[0], w1 = wa[1], w2 = wa[2], w3 = wa[3];
  float w4 = wb[0], w5 = wb[1], w6 = wb[2], w7 = wb[3];
  uint4v a1w, a2w;
  a1w.x = pack_bf16_trunc(w0, w1);
  a1w.y = pack_bf16_trunc(w2, w3);
  a1w.z = pack_bf16_trunc(w4, w5);
  a1w.w = pack_bf16_trunc(w6, w7);
  unsigned l0 = pack_bf16_trunc(bf16_resid(w0), bf16_resid(w1));
  unsigned l1 = pack_bf16_trunc(bf16_resid(w2), bf16_resid(w3));
  unsigned l2 = pack_bf16_trunc(bf16_resid(w4), bf16_resid(w5));
  unsigned l3 = pack_bf16_trunc(bf16_resid(w6), bf16_resid(w7));
  a2w.x = odd ? 0u : l0;
  a2w.y = odd ? 0u : l1;
  a2w.z = odd ? 0u : l2;
  a2w.w = odd ? 0u : l3;
  const short8v A1 = __builtin_bit_cast(short8v, a1w);
  const short8v A2 = __builtin_bit_cast(short8v, a2w);

  // ---- per-lane output-row (m = 4g+r) constants ----
  const int m0 = 4 * g;
  const float wih0 = Wih[m0 + 0], wih1 = Wih[m0 + 1], wih2 = Wih[m0 + 2], wih3 = Wih[m0 + 3];
  const float bt0 = bih[m0 + 0] + bhh[m0 + 0];
  const float bt1 = bih[m0 + 1] + bhh[m0 + 1];
  const float bt2 = bih[m0 + 2] + bhh[m0 + 2];
  const float bt3 = bih[m0 + 3] + bhh[m0 + 3];
  const float fw0 = fcw[m0 + 0], fw1 = fcw[m0 + 1], fw2 = fcw[m0 + 2], fw3 = fcw[m0 + 3];

  // ---- state ----
  short8v Bfrag = {0, 0, 0, 0, 0, 0, 0, 0};
  float h0 = 0.f, h1 = 0.f, h2 = 0.f, h3 = 0.f;

  const float* xr = x + (size_t)b * T_LEN;
  float4v c0 = *reinterpret_cast<const float4v*>(xr);
  float4v c1 = *reinterpret_cast<const float4v*>(xr + 4);

#define STEP(XV)                                                               \
  do {                                                                         \
    float4v cA;                                                                \
    cA[0] = fmaf((XV), wih0, bt0);                                             \
    cA[1] = fmaf((XV), wih1, bt1);                                             \
    cA[2] = fmaf((XV), wih2, bt2);                                             \
    cA[3] = fmaf((XV), wih3, bt3);                                             \
    cA = __builtin_amdgcn_mfma_f32_16x16x32_bf16(A1, Bfrag, cA, 0, 0, 0);      \
    cA = __builtin_amdgcn_mfma_f32_16x16x32_bf16(A2, Bfrag, cA, 0, 0, 0);      \
    h0 = fast_tanh(cA[0]);                                                     \
    h1 = fast_tanh(cA[1]);                                                     \
    h2 = fast_tanh(cA[2]);                                                     \
    h3 = fast_tanh(cA[3]);                                                     \
    unsigned hp0 = pack_bf16_trunc(h0, h1);                                    \
    unsigned hp1 = pack_bf16_trunc(h2, h3);                                    \
    unsigned lp0 = pack_bf16_trunc(bf16_resid(h0), bf16_resid(h1));            \
    unsigned lp1 = pack_bf16_trunc(bf16_resid(h2), bf16_resid(h3));            \
    unsigned php0 = (unsigned)__shfl_xor((int)hp0, 16, 64);                    \
    unsigned php1 = (unsigned)__shfl_xor((int)hp1, 16, 64);                    \
    unsigned plp0 = (unsigned)__shfl_xor((int)lp0, 16, 64);                    \
    unsigned plp1 = (unsigned)__shfl_xor((int)lp1, 16, 64);                    \
    uint4v bw;                                                                 \
    bw.x = odd ? plp0 : hp0;                                                   \
    bw.y = odd ? plp1 : hp1;                                                   \
    bw.z = odd ? lp0 : php0;                                                   \
    bw.w = odd ? lp1 : php1;                                                   \
    Bfrag = __builtin_bit_cast(short8v, bw);                                   \
  } while (0)

  for (int it = 0; it < T_LEN / 4; ++it) {
    int pf = it + 2;
    pf = (pf < T_LEN / 4) ? pf : (T_LEN / 4 - 1);
    float4v nx = *reinterpret_cast<const float4v*>(xr + 4 * pf);
    STEP(c0[0]);
    STEP(c0[1]);
    STEP(c0[2]);
    STEP(c0[3]);
    c0 = c1;
    c1 = nx;
  }
#undef STEP

  // ---- fc + sigmoid on final h ----
  float s = h0 * fw0;
  s = fmaf(h1, fw1, s);
  s = fmaf(h2, fw2, s);
  s = fmaf(h3, fw3, s);
  s += __shfl_xor(s, 16, 64);
  s += __shfl_xor(s, 32, 64);
  if (g == 0) {
    float y = s + fcb[0];
    float t = fminf(fmaxf(-1.4426950408889634f * y, -126.0f), 126.0f);
    float e = __builtin_amdgcn_exp2f(t);
    out[b] = __builtin_amdgcn_rcpf(1.0f + e);
  }
}

extern "C" void kernel_launch(void* const* d_in, const int* in_sizes, int n_in,
                              void* d_out, int out_size, void* d_ws, size_t ws_size,
                              hipStream_t stream) {
  const float* x   = (const float*)d_in[0];
  const float* Wih = (const float*)d_in[1];
  const float* Whh = (const float*)d_in[2];
  const float* bih = (const float*)d_in[3];
  const float* bhh = (const float*)d_in[4];
  const float* fcw = (const float*)d_in[5];
  const float* fcb = (const float*)d_in[6];
  float* out = (float*)d_out;

  const int B = in_sizes[0] / T_LEN;      // 16384
  const int groups = B / 16;              // 1024 waves
  const int blocks = groups / 4;          // 256 blocks x 256 threads
  elman_kernel<<<blocks, 256, 0, stream>>>(x, Wih, Whh, bih, bhh, fcw, fcb, out);
}

// Round 4
// 266.239 us; speedup vs baseline: 1.4761x; 1.4761x over previous
//
#include <hip/hip_runtime.h>

#define T_LEN 2048
#define HID 16

typedef __attribute__((ext_vector_type(8))) short short8v;
typedef __attribute__((ext_vector_type(4))) float float4v;
typedef __attribute__((ext_vector_type(4))) unsigned int uint4v;

// RNE bf16 of a float, returned in the HIGH 16 bits (low 16 zero)
__device__ __forceinline__ unsigned bf16_bits_hi(float a) {
  unsigned u = __builtin_bit_cast(unsigned, a);
  u += 0x7FFFu + ((u >> 16) & 1u);
  return u & 0xFFFF0000u;
}
// RNE-packed bf16 pair: word = [bf16(a) | bf16(b)<<16]
__device__ __forceinline__ unsigned pack2_rn(float a, float b) {
  return (bf16_bits_hi(a) >> 16) | bf16_bits_hi(b);
}
// RNE bf16 value of w, as float
__device__ __forceinline__ float bf16_val(float w) {
  return __builtin_bit_cast(float, bf16_bits_hi(w));
}

// tanh(y) with y pre-scaled: input is s = 2*log2(e)*y; tanh = 1 - 2/(exp2(s)+1)
__device__ __forceinline__ float tanh_pre(float s) {
  float e = __builtin_amdgcn_exp2f(s);
  float r = __builtin_amdgcn_rcpf(e + 1.0f);
  return fmaf(-2.0f, r, 1.0f);
}

// One wave = 16 batch columns, mfma_f32_16x16x32_bf16 (layouts verified in R2 pass):
//   A: lane l holds A[l&15][8*(l>>4)+v]; B: lane holds B[8*(l>>4)+v][l&15];
//   D: lane holds D[4*(l>>4)+r][l&15].
// k-slot permutation: slot (g, v) represents h-row 4g+(v&3)  => each lane's B-frag
// is its OWN 4 D-values (tanh'd, bf16) duplicated: ZERO cross-lane traffic.
// Duplicate slots carry W_hi (v<4) and W_lo (v>=4): one MFMA = full-precision W*h.
// W_hh, W_ih, biases pre-scaled by 2*log2(e) so tanh needs no pre-multiply.
__global__ __launch_bounds__(256) void elman_kernel(
    const float* __restrict__ x, const float* __restrict__ Wih,
    const float* __restrict__ Whh, const float* __restrict__ bih,
    const float* __restrict__ bhh, const float* __restrict__ fcw,
    const float* __restrict__ fcb, float* __restrict__ out) {
  const int tid  = threadIdx.x;
  const int lane = tid & 63;
  const int wv   = tid >> 6;
  const int grp  = blockIdx.x * 4 + wv;
  const int g    = lane >> 4;          // k-block / D-row group
  const int j    = lane & 15;          // batch col n; also A row m
  const int b    = grp * 16 + j;

  const float KS = 2.885390081777927f;  // 2*log2(e)

  // ---- A operand: row j of KS*W_hh, cols 4g..4g+3, split hi/lo into slots ----
  const float* wrow = Whh + j * HID + 4 * g;
  float4v wq = *reinterpret_cast<const float4v*>(wrow);
  float w0 = KS * wq[0], w1 = KS * wq[1], w2 = KS * wq[2], w3 = KS * wq[3];
  uint4v aw;
  aw.x = pack2_rn(w0, w1);                                   // hi parts (RNE)
  aw.y = pack2_rn(w2, w3);
  aw.z = pack2_rn(w0 - bf16_val(w0), w1 - bf16_val(w1));     // residuals
  aw.w = pack2_rn(w2 - bf16_val(w2), w3 - bf16_val(w3));
  const short8v Afrag = __builtin_bit_cast(short8v, aw);

  // ---- per-lane output-row (m = 4g+r) constants, pre-scaled by KS ----
  const int m0 = 4 * g;
  const float wih0 = KS * Wih[m0 + 0], wih1 = KS * Wih[m0 + 1];
  const float wih2 = KS * Wih[m0 + 2], wih3 = KS * Wih[m0 + 3];
  const float bt0 = KS * (bih[m0 + 0] + bhh[m0 + 0]);
  const float bt1 = KS * (bih[m0 + 1] + bhh[m0 + 1]);
  const float bt2 = KS * (bih[m0 + 2] + bhh[m0 + 2]);
  const float bt3 = KS * (bih[m0 + 3] + bhh[m0 + 3]);
  const float fw0 = fcw[m0 + 0], fw1 = fcw[m0 + 1], fw2 = fcw[m0 + 2], fw3 = fcw[m0 + 3];

  // ---- state ----
  short8v Bfrag = {0, 0, 0, 0, 0, 0, 0, 0};
  float h0 = 0.f, h1 = 0.f, h2 = 0.f, h3 = 0.f;

  const float* xr = x + (size_t)b * T_LEN;
  float4v c0 = *reinterpret_cast<const float4v*>(xr);
  float4v c1 = *reinterpret_cast<const float4v*>(xr + 4);

#define STEP(XV)                                                               \
  do {                                                                         \
    float4v cA;                                                                \
    cA[0] = fmaf((XV), wih0, bt0);                                             \
    cA[1] = fmaf((XV), wih1, bt1);                                             \
    cA[2] = fmaf((XV), wih2, bt2);                                             \
    cA[3] = fmaf((XV), wih3, bt3);                                             \
    cA = __builtin_amdgcn_mfma_f32_16x16x32_bf16(Afrag, Bfrag, cA, 0, 0, 0);   \
    h0 = tanh_pre(cA[0]);                                                      \
    h1 = tanh_pre(cA[1]);                                                      \
    h2 = tanh_pre(cA[2]);                                                      \
    h3 = tanh_pre(cA[3]);                                                      \
    unsigned hp0 = pack2_rn(h0, h1);                                           \
    unsigned hp1 = pack2_rn(h2, h3);                                           \
    uint4v bw;                                                                 \
    bw.x = hp0; bw.y = hp1; bw.z = hp0; bw.w = hp1;                            \
    Bfrag = __builtin_bit_cast(short8v, bw);                                   \
  } while (0)

  for (int it = 0; it < T_LEN / 4; ++it) {
    int pf = it + 2;
    pf = (pf < T_LEN / 4) ? pf : (T_LEN / 4 - 1);
    float4v nx = *reinterpret_cast<const float4v*>(xr + 4 * pf);
    STEP(c0[0]);
    STEP(c0[1]);
    STEP(c0[2]);
    STEP(c0[3]);
    c0 = c1;
    c1 = nx;
  }
#undef STEP

  // ---- fc + sigmoid on final h ----
  float s = h0 * fw0;
  s = fmaf(h1, fw1, s);
  s = fmaf(h2, fw2, s);
  s = fmaf(h3, fw3, s);
  s += __shfl_xor(s, 16, 64);
  s += __shfl_xor(s, 32, 64);
  if (g == 0) {
    float y = s + fcb[0];
    float t = fminf(fmaxf(-1.4426950408889634f * y, -126.0f), 126.0f);
    float e = __builtin_amdgcn_exp2f(t);
    out[b] = __builtin_amdgcn_rcpf(1.0f + e);
  }
}

extern "C" void kernel_launch(void* const* d_in, const int* in_sizes, int n_in,
                              void* d_out, int out_size, void* d_ws, size_t ws_size,
                              hipStream_t stream) {
  const float* x   = (const float*)d_in[0];
  const float* Wih = (const float*)d_in[1];
  const float* Whh = (const float*)d_in[2];
  const float* bih = (const float*)d_in[3];
  const float* bhh = (const float*)d_in[4];
  const float* fcw = (const float*)d_in[5];
  const float* fcb = (const float*)d_in[6];
  float* out = (float*)d_out;

  const int B = in_sizes[0] / T_LEN;      // 16384
  const int groups = B / 16;              // 1024 waves -> 1 per SIMD machine-wide
  const int blocks = groups / 4;          // 256 blocks x 256 threads
  elman_kernel<<<blocks, 256, 0, stream>>>(x, Wih, Whh, bih, bhh, fcw, fcb, out);
}

// Round 5
// 225.547 us; speedup vs baseline: 1.7424x; 1.1804x over previous
//
#include <hip/hip_runtime.h>

#define T_LEN 2048
#define HID 16

typedef __attribute__((ext_vector_type(8))) short short8v;
typedef __attribute__((ext_vector_type(4))) float float4v;
typedef __attribute__((ext_vector_type(4))) unsigned int uint4v;

// ---- prologue-only helpers (integer RNE bf16; not on the hot chain) ----
__device__ __forceinline__ unsigned bf16_bits_hi(float a) {
  unsigned u = __builtin_bit_cast(unsigned, a);
  u += 0x7FFFu + ((u >> 16) & 1u);
  return u & 0xFFFF0000u;
}
__device__ __forceinline__ unsigned pack2_rn(float a, float b) {
  return (bf16_bits_hi(a) >> 16) | bf16_bits_hi(b);
}
__device__ __forceinline__ float bf16_val(float w) {
  return __builtin_bit_cast(float, bf16_bits_hi(w));
}

// hot-path: single-instruction packed f32->bf16x2 (RNE)
__device__ __forceinline__ unsigned cvtpk(float a, float b) {
  unsigned r;
  asm("v_cvt_pk_bf16_f32 %0, %1, %2" : "=v"(r) : "v"(a), "v"(b));
  return r;
}

// One wave = 16 batch columns, mfma_f32_16x16x32_bf16 (layouts verified R2/R4):
//   A: lane l holds A[l&15][8*(l>>4)+v]; B: lane holds B[8*(l>>4)+v][l&15];
//   D: lane holds D[4*(l>>4)+r][l&15].
// k-slot permutation: slot (g,v) carries logical h-row 4g+(v&3) => each lane's
// B-frag is its OWN 4 D-derived values: ZERO cross-lane traffic.
// Slots v<4 carry A_hi, v>=4 carry A_lo (exact bf16 hi/lo split of -2*KS*W_hh).
// Recurrence in sigmoid space:  s_t = C_t + (-2*KS*W) * r_{t-1},
//   r = 1/(1+2^s)  (h = 1-2r),  C_t = KS*(wih*x_t + b_ih + b_hh + rowsum(W_hh)).
// Chain per step: MFMA -> exp2 -> add1 -> rcp -> cvt_pk -> MFMA.
__global__ __launch_bounds__(256) void elman_kernel(
    const float* __restrict__ x, const float* __restrict__ Wih,
    const float* __restrict__ Whh, const float* __restrict__ bih,
    const float* __restrict__ bhh, const float* __restrict__ fcw,
    const float* __restrict__ fcb, float* __restrict__ out) {
  const int tid  = threadIdx.x;
  const int lane = tid & 63;
  const int wv   = tid >> 6;
  const int grp  = blockIdx.x * 4 + wv;
  const int g    = lane >> 4;          // k-block / D-row group
  const int j    = lane & 15;          // batch col n; also A row m
  const int b    = grp * 16 + j;

  const float KS = 2.885390081777927f;  // 2*log2(e)

  // ---- A operand: row j of (-2*KS*W_hh), cols 4g..4g+3, hi/lo split ----
  const float* wrow = Whh + j * HID + 4 * g;
  float4v wq = *reinterpret_cast<const float4v*>(wrow);
  const float WS = -2.0f * KS;
  float w0 = WS * wq[0], w1 = WS * wq[1], w2 = WS * wq[2], w3 = WS * wq[3];
  uint4v aw;
  aw.x = pack2_rn(w0, w1);                                   // hi parts (RNE)
  aw.y = pack2_rn(w2, w3);
  aw.z = pack2_rn(w0 - bf16_val(w0), w1 - bf16_val(w1));     // exact residuals
  aw.w = pack2_rn(w2 - bf16_val(w2), w3 - bf16_val(w3));
  const short8v Afrag = __builtin_bit_cast(short8v, aw);

  // ---- per-lane output-row (m = 4g+r) constants ----
  const int m0 = 4 * g;
  float wihK[4], btK[4], fwv[4];
  #pragma unroll
  for (int r = 0; r < 4; ++r) {
    const int m = m0 + r;
    // rowsum(W_hh[m,:]) — prologue only, W is 1KB (L2-resident)
    float rs = 0.f;
    #pragma unroll
    for (int q = 0; q < 4; ++q) {
      float4v t = *reinterpret_cast<const float4v*>(Whh + m * HID + 4 * q);
      rs += t[0] + t[1] + t[2] + t[3];
    }
    wihK[r] = KS * Wih[m];
    btK[r]  = KS * (bih[m] + bhh[m] + rs);
    fwv[r]  = fcw[m];
  }

  // ---- state: h=0 -> r=0.5 (bf16 0x3F00 exact) ----
  uint4v bw0; bw0.x = 0x3F003F00u; bw0.y = 0x3F003F00u;
  bw0.z = 0x3F003F00u; bw0.w = 0x3F003F00u;
  short8v Bfrag = __builtin_bit_cast(short8v, bw0);
  float r0 = 0.5f, r1 = 0.5f, r2 = 0.5f, r3 = 0.5f;

  const float* xr = x + (size_t)b * T_LEN;
  float4v c0 = *reinterpret_cast<const float4v*>(xr);
  float4v c1 = *reinterpret_cast<const float4v*>(xr + 4);

#define STEP(XV)                                                               \
  do {                                                                         \
    float4v cA;                                                                \
    cA[0] = fmaf((XV), wihK[0], btK[0]);                                       \
    cA[1] = fmaf((XV), wihK[1], btK[1]);                                       \
    cA[2] = fmaf((XV), wihK[2], btK[2]);                                       \
    cA[3] = fmaf((XV), wihK[3], btK[3]);                                       \
    cA = __builtin_amdgcn_mfma_f32_16x16x32_bf16(Afrag, Bfrag, cA, 0, 0, 0);   \
    float e0 = __builtin_amdgcn_exp2f(cA[0]);                                  \
    float e1 = __builtin_amdgcn_exp2f(cA[1]);                                  \
    float e2 = __builtin_amdgcn_exp2f(cA[2]);                                  \
    float e3 = __builtin_amdgcn_exp2f(cA[3]);                                  \
    r0 = __builtin_amdgcn_rcpf(e0 + 1.0f);                                     \
    r1 = __builtin_amdgcn_rcpf(e1 + 1.0f);                                     \
    r2 = __builtin_amdgcn_rcpf(e2 + 1.0f);                                     \
    r3 = __builtin_amdgcn_rcpf(e3 + 1.0f);                                     \
    uint4v bw;                                                                 \
    bw.x = cvtpk(r0, r1);                                                      \
    bw.y = cvtpk(r2, r3);                                                      \
    bw.z = cvtpk(r0, r1);                                                      \
    bw.w = cvtpk(r2, r3);                                                      \
    Bfrag = __builtin_bit_cast(short8v, bw);                                   \
  } while (0)

  for (int it = 0; it < T_LEN / 4; ++it) {
    int pf = it + 2;
    pf = (pf < T_LEN / 4) ? pf : (T_LEN / 4 - 1);
    float4v nx = *reinterpret_cast<const float4v*>(xr + 4 * pf);
    STEP(c0[0]);
    STEP(c0[1]);
    STEP(c0[2]);
    STEP(c0[3]);
    c0 = c1;
    c1 = nx;
  }
#undef STEP

  // ---- fc + sigmoid on final h = 1-2r ----
  float h0 = fmaf(-2.f, r0, 1.f);
  float h1 = fmaf(-2.f, r1, 1.f);
  float h2 = fmaf(-2.f, r2, 1.f);
  float h3 = fmaf(-2.f, r3, 1.f);
  float s = h0 * fwv[0];
  s = fmaf(h1, fwv[1], s);
  s = fmaf(h2, fwv[2], s);
  s = fmaf(h3, fwv[3], s);
  s += __shfl_xor(s, 16, 64);
  s += __shfl_xor(s, 32, 64);
  if (g == 0) {
    float y = s + fcb[0];
    float t = fminf(fmaxf(-1.4426950408889634f * y, -126.0f), 126.0f);
    float e = __builtin_amdgcn_exp2f(t);
    out[b] = __builtin_amdgcn_rcpf(1.0f + e);
  }
}

extern "C" void kernel_launch(void* const* d_in, const int* in_sizes, int n_in,
                              void* d_out, int out_size, void* d_ws, size_t ws_size,
                              hipStream_t stream) {
  const float* x   = (const float*)d_in[0];
  const float* Wih = (const float*)d_in[1];
  const float* Whh = (const float*)d_in[2];
  const float* bih = (const float*)d_in[3];
  const float* bhh = (const float*)d_in[4];
  const float* fcw = (const float*)d_in[5];
  const float* fcb = (const float*)d_in[6];
  float* out = (float*)d_out;

  const int B = in_sizes[0] / T_LEN;      // 16384
  const int groups = B / 16;              // 1024 waves -> 1 per SIMD machine-wide
  const int blocks = groups / 4;          // 256 blocks x 256 threads
  elman_kernel<<<blocks, 256, 0, stream>>>(x, Wih, Whh, bih, bhh, fcw, fcb, out);
}